// Round 1
// 89.984 us; speedup vs baseline: 1.0634x; 1.0634x over previous
//
#include <hip/hip_runtime.h>
#include <math.h>

#define BB 64
#define TT 2048
#define HIDD 256
#define FASTN 64
#define SLOWN 256
#define VOC 64
#define TLOOP (TT - 3)   // 2045 scan steps
#define NEGC -1000000000.0f
#define EPAD 257         // padded emb row stride (bank-conflict-free)
#define NEGBIG (-(1 << 20))
#define BYTEAT(U, J) ((int)(((U) >> (8 * (J))) & 0xFFu))
#define NW 16            // waves per block (was 8)
#define NT (NW * 64)     // 1024 threads

// ---------------------------------------------------------------------------
// Single fused kernel (64 blocks x 1024 = 16 waves). vs previous version:
//  - 16 scan segments (half the serial bytes/lane), 16 waves for latency hiding
//  - Wo NOT staged (read once per block -> direct coalesced global, L2-hot)
//  - act+rank merged into one wave-0 region (one barrier fewer)
// Algorithm unchanged:
//  1. stage emb (padded) into LDS; seq into registers (int2/thread).
//  2. gate/dem dots -> act, dem; rank (ascending dem, tie by id) -> prS/invS.
//  3. pack rank stream (0xFF = inactive) -> compact to zsB via prefix sums.
//  4. time-parallel Lindley scan: step f(a)=max(a+p,q); fill (p,q)=(x,-inf),
//     LRU (p,q)=(x-1,x); maps compose associatively -> segment (P,Q).
//     Pass1: 16 segments' (P,Q) in parallel; combine -> per-wave entry a;
//     Pass2: rerun for final a + windowed eviction counts e (slow FIFO ring
//     = last min(n,256) evictions). Token counts = adjacent lane diffs.
//  5. qLast = emb[lastv] @ Wq + bq (per-block GEMV, Wq L2-resident).
//  6. scores -> count-weighted softmax regroup -> ctx -> logits; slow_mask.
// ---------------------------------------------------------------------------
__global__ __launch_bounds__(NT) void k_one(
    const int* __restrict__ seq, const float* __restrict__ emb,
    const float* __restrict__ Wg, const float* __restrict__ bg,
    const float* __restrict__ Wd, const float* __restrict__ bd,
    const float* __restrict__ Wq, const float* __restrict__ bq,
    const float* __restrict__ Wo, const float* __restrict__ bo,
    float* __restrict__ out) {
  const int b = blockIdx.x;
  const int tid = threadIdx.x;
  const int lane = tid & 63;
  const int wv = tid >> 6;

  __shared__ float embS[VOC * EPAD];                    // 65792 B
  __shared__ __align__(16) unsigned char zsB[2080];
  __shared__ float qLastS[HIDD], ctxS[HIDD];
  __shared__ float pp16[NW][64];                        // scores/logits partials
  __shared__ float gp16[NW][64], dp16[NW][64];
  __shared__ float qp4[4][HIDD];                        // qLast / ctx partials
  __shared__ float demS[64], wS[64];
  __shared__ int prS[64], invS[64], cntTok[64];
  __shared__ int CS[NW];
  __shared__ int PsS[NW][64], QsS[NW][64], aEndS[NW][64], eSS[NW][64];

  // ---- entry: seq into regs; stage emb (padded) ----
  const int2 sq = ((const int2*)(seq + b * TT))[tid];   // tokens 2t, 2t+1
  const int lastv = seq[b * TT + TT - 1];
  const float4* emb4 = (const float4*)emb;
  for (int i = tid; i < VOC * 64; i += NT) {
    float4 e = emb4[i];
    float* d = &embS[(i >> 6) * EPAD + ((i & 63) << 2)];
    d[0] = e.x; d[1] = e.y; d[2] = e.z; d[3] = e.w;
  }
  __syncthreads();

  // ---- gate/dem partial dots: thread = (v, kp in 0..15), 16 k each ----
  {
    const int v = tid & 63, kp = tid >> 6;
    const float* er = &embS[v * EPAD + kp * 16];
    const float* wg = &Wg[kp * 16];
    const float* wd = &Wd[kp * 16];
    float g = 0.f, d = 0.f;
#pragma unroll
    for (int k = 0; k < 16; ++k) { float e = er[k]; g += e * wg[k]; d += e * wd[k]; }
    gp16[kp][v] = g; dp16[kp][v] = d;
  }
  __syncthreads();
  // ---- act + rank merged (wave 0 only; wave-synchronous LDS, no barrier) ----
  if (tid < 64) {
    float g = bg[0], d = bd[0];
#pragma unroll
    for (int p = 0; p < NW; ++p) { g += gp16[p][tid]; d += dp16[p][tid]; }
    int act = (1.f / (1.f + expf(-g)) >= 0.4f) ? 1 : 0;
    demS[tid] = d;
    // same-wave LDS write->read: lockstep + compiler lgkmcnt, no barrier needed
    float dv = d;
    int r = 0;
    for (int u2 = 0; u2 < 64; ++u2) {
      float du = demS[u2];
      r += (du < dv || (du == dv && u2 < tid)) ? 1 : 0;
    }
    invS[r] = tid;
    prS[tid] = act ? r : 0xFF;
  }
  __syncthreads();

  // ---- pack 2 tokens -> rank bytes; per-wave prefix; scatter to zsB ----
  const int t0 = tid * 2;
  int by0, by1, c;
  {
    int r0 = prS[sq.x], r1 = prS[sq.y];
    by0 = (t0 < TLOOP) ? r0 : 0xFF;
    by1 = (t0 + 1 < TLOOP) ? r1 : 0xFF;
    c = ((by0 != 0xFF) ? 1 : 0) + ((by1 != 0xFF) ? 1 : 0);
  }
  int incl = c;
  for (int s = 1; s < 64; s <<= 1) {
    int t = __shfl_up(incl, s);
    if (lane >= s) incl += t;
  }
  if (lane == 63) CS[wv] = incl;
  __syncthreads();

  int Ow = 0, A = 0;
#pragma unroll
  for (int w2 = 0; w2 < NW; ++w2) {
    int cw = CS[w2];
    Ow += (w2 < wv) ? cw : 0;
    A += cw;
  }
  {
    int pos = Ow + incl - c;
    if (by0 != 0xFF) zsB[pos++] = (unsigned char)by0;
    if (by1 != 0xFF) zsB[pos++] = (unsigned char)by1;
  }
  __syncthreads();

  const int fsplit = A < 64 ? A : 64;
  const int nL = A - fsplit;
  const int win = nL < 256 ? nL : 256;
  const int wstart = A - win;
  const int L = (((A + NW - 1) / NW) + 15) & ~15;  // seg len, mult of 16
  const int baseW = wv * L;
  const int endW = min(baseW + L, A);

  // ---- pass 1: per-segment map (P,Q), lane = rank threshold ----
  int P = 0, Q = NEGBIG;
  for (int g = baseW; g < endW; g += 16) {
    uint4 t4 = *(const uint4*)(zsB + g);
    unsigned dsw[4] = {t4.x, t4.y, t4.z, t4.w};
    const int gHi = min(g + 16, endW);
    if (gHi == g + 16 && gHi <= fsplit) {            // FILL
#pragma unroll
      for (int d = 0; d < 4; ++d)
#pragma unroll
        for (int j = 0; j < 4; ++j) {
          int x = (BYTEAT(dsw[d], j) <= lane) ? 1 : 0;
          P += x; Q += x;
        }
    } else if (gHi == g + 16 && g >= fsplit) {       // LRU
#pragma unroll
      for (int d = 0; d < 4; ++d)
#pragma unroll
        for (int j = 0; j < 4; ++j) {
          int x = (BYTEAT(dsw[d], j) <= lane) ? 1 : 0;
          P += x - 1;
          Q = max(Q + x - 1, x);
        }
    } else {                                         // GATED
#pragma unroll
      for (int d = 0; d < 4; ++d)
#pragma unroll
        for (int j = 0; j < 4; ++j) {
          int i = g + d * 4 + j;
          int x = (BYTEAT(dsw[d], j) <= lane) ? 1 : 0;
          bool vld = i < endW;
          bool fil = i < fsplit;
          int p = fil ? x : x - 1;
          int q = fil ? NEGBIG : x;
          int Pn = P + p;
          int Qn = max(Q + p, q);
          P = vld ? Pn : P;
          Q = vld ? Qn : Q;
        }
    }
  }
  PsS[wv][lane] = P;
  QsS[wv][lane] = Q;
  __syncthreads();

  // ---- combine: entry value for my segment ----
  int a = 0;
  for (int w2 = 0; w2 < wv; ++w2)
    a = max(a + PsS[w2][lane], QsS[w2][lane]);

  // ---- pass 2: rerun segment for final a + windowed eviction count e ----
  int e = 0;
  for (int g = baseW; g < endW; g += 16) {
    uint4 t4 = *(const uint4*)(zsB + g);
    unsigned dsw[4] = {t4.x, t4.y, t4.z, t4.w};
    const int gHi = min(g + 16, endW);
    const bool full = (gHi == g + 16);
    if (full && gHi <= fsplit) {                     // FILL
#pragma unroll
      for (int d = 0; d < 4; ++d)
#pragma unroll
        for (int j = 0; j < 4; ++j)
          a += (BYTEAT(dsw[d], j) <= lane) ? 1 : 0;
    } else if (full && g >= fsplit && gHi <= wstart) {  // MAIN
#pragma unroll
      for (int d = 0; d < 4; ++d)
#pragma unroll
        for (int j = 0; j < 4; ++j) {
          int xm1 = (BYTEAT(dsw[d], j) <= lane) ? 0 : -1;
          a = max(a, 1) + xm1;
        }
    } else if (full && g >= wstart) {                // WIN
#pragma unroll
      for (int d = 0; d < 4; ++d)
#pragma unroll
        for (int j = 0; j < 4; ++j) {
          int xm1 = (BYTEAT(dsw[d], j) <= lane) ? 0 : -1;
          e += (a > 0) ? 1 : 0;
          a = max(a, 1) + xm1;
        }
    } else {                                         // GATED
#pragma unroll
      for (int d = 0; d < 4; ++d)
#pragma unroll
        for (int j = 0; j < 4; ++j) {
          int i = g + d * 4 + j;
          int x = (BYTEAT(dsw[d], j) <= lane) ? 1 : 0;
          bool vld = i < endW;
          bool fil = i < fsplit;
          bool wg = vld && (i >= wstart);
          e += (wg && a > 0) ? 1 : 0;
          int af = a + x;
          int al = max(a, 1) + (x - 1);
          int an = fil ? af : al;
          a = vld ? an : a;
        }
    }
  }
  aEndS[wv][lane] = a;
  eSS[wv][lane] = e;
  __syncthreads();

  // ---- finalize counts (wave 0) ----
  if (tid < 64) {
    int af = aEndS[NW - 1][lane];
    int et = 0;
#pragma unroll
    for (int w2 = 0; w2 < NW; ++w2) et += eSS[w2][lane];
    int ap = __shfl_up(af, 1); if (lane == 0) ap = 0;
    int ep = __shfl_up(et, 1); if (lane == 0) ep = 0;
    cntTok[invS[lane]] = (af - ap) + (et - ep);
  }

  // ---- qLast = emb[lastv] @ Wq + bq  (1024 threads, 4 k-quarters) ----
  {
    const int j = tid & 255, kq = tid >> 8;
    const float* eL = &embS[lastv * EPAD + kq * 64];
    const float* wq = &Wq[(kq * 64) * HIDD + j];
    float acc = 0.f;
#pragma unroll 8
    for (int k = 0; k < 64; ++k) acc += eL[k] * wq[k * HIDD];
    qp4[kq][j] = acc;
  }
  __syncthreads();
  if (tid < 256)
    qLastS[tid] = qp4[0][tid] + qp4[1][tid] + qp4[2][tid] + qp4[3][tid] + bq[tid];
  __syncthreads();

  // ---- scores sc[v] = emb[v].qLast ; softmax regroup over counts ----
  {
    const int v = tid & 63, part = tid >> 6;
    const float* er = &embS[v * EPAD + part * 16];
    const float* qr = &qLastS[part * 16];
    float s = 0.f;
#pragma unroll
    for (int k = 0; k < 16; ++k) s += er[k] * qr[k];
    pp16[part][v] = s;
  }
  __syncthreads();
  if (tid < 64) {
    float sc = 0.f;
#pragma unroll
    for (int p = 0; p < NW; ++p) sc += pp16[p][tid];
    int cc = cntTok[tid];
    float m = (cc > 0) ? sc : NEGC;
    for (int off = 32; off; off >>= 1) m = fmaxf(m, __shfl_xor(m, off));
    float w = (cc > 0) ? (float)cc * expf(sc - m) : 0.f;
    float z = w;
    for (int off = 32; off; off >>= 1) z += __shfl_xor(z, off);
    z += (float)(FASTN + SLOWN - (fsplit + win)) * expf(NEGC - m);
    wS[tid] = w / z;
  }
  __syncthreads();

  // ---- ctx[h] = sum_u wS[u] * emb[u][h]  (1024 threads, 4 u-quarters) ----
  {
    const int h = tid & 255, part = tid >> 8;
    float cacc = 0.f;
#pragma unroll
    for (int u = 0; u < 16; ++u)
      cacc += wS[part * 16 + u] * embS[(part * 16 + u) * EPAD + h];
    qp4[part][h] = cacc;   // reuse qp4
  }
  __syncthreads();
  if (tid < 256)
    ctxS[tid] = qp4[0][tid] + qp4[1][tid] + qp4[2][tid] + qp4[3][tid];
  __syncthreads();

  // ---- logits = ctx @ Wo + bo  (Wo direct from global, coalesced, L2-hot) ----
  {
    const int o = tid & 63, part = tid >> 6;
    const float* cr = &ctxS[part * 16];
    const float* wr = &Wo[(part * 16) * VOC + o];
    float s = 0.f;
#pragma unroll
    for (int k = 0; k < 16; ++k) s += cr[k] * wr[k * VOC];
    pp16[part][o] = s;
  }
  __syncthreads();
  if (tid < 64) {
    float s = bo[tid];
#pragma unroll
    for (int p = 0; p < NW; ++p) s += pp16[p][tid];
    out[b * VOC + tid] = s;
  }
  if (tid < 256)
    out[BB * VOC + b * SLOWN + tid] = (tid < win) ? 1.0f : 0.0f;
}

// ---------------------------------------------------------------------------
extern "C" void kernel_launch(void* const* d_in, const int* in_sizes, int n_in,
                              void* d_out, int out_size, void* d_ws, size_t ws_size,
                              hipStream_t stream) {
  const int*   seq = (const int*)d_in[0];
  const float* emb = (const float*)d_in[1];
  const float* Wg  = (const float*)d_in[2];
  const float* bg  = (const float*)d_in[3];
  const float* Wd  = (const float*)d_in[4];
  const float* bd  = (const float*)d_in[5];
  const float* Wq  = (const float*)d_in[6];
  const float* bq  = (const float*)d_in[7];
  const float* Wo  = (const float*)d_in[8];
  const float* bo  = (const float*)d_in[9];
  float* out = (float*)d_out;

  k_one<<<dim3(64), dim3(NT), 0, stream>>>(seq, emb, Wg, bg, Wd, bd,
                                           Wq, bq, Wo, bo, out);
}

// Round 2
// 88.564 us; speedup vs baseline: 1.0804x; 1.0160x over previous
//
#include <hip/hip_runtime.h>
#include <math.h>

#define BB 64
#define TT 2048
#define HIDD 256
#define FASTN 64
#define SLOWN 256
#define VOC 64
#define TLOOP (TT - 3)   // 2045 scan steps
#define NEGC -1000000000.0f
#define EPAD 257         // padded emb row stride (bank-conflict-free)
#define NEGBIG (-(1 << 20))
#define BYTEAT(U, J) ((int)(((U) >> (8 * (J))) & 0xFFu))
#define NW 16            // waves per block
#define NT (NW * 64)     // 1024 threads

// ---------------------------------------------------------------------------
// Single fused kernel (64 blocks x 1024 = 16 waves). vs previous version:
//  - Wq GEMV loads software-pipelined under pass1/pass2 (T14 async split)
//  - pass 2 only for waves whose segment overlaps the eviction window;
//    final Lindley value from associative combine of all 16 (P,Q) maps
//  - Wo prefetched to registers before the scores phase
//  - ctx computed directly by 256 threads (one barrier fewer)
//  - slow_mask stored early (overlapped with the scan)
// Algorithm unchanged:
//  1. stage emb (padded) into LDS; seq into registers (int2/thread).
//  2. gate/dem dots -> act, dem; rank (ascending dem, tie by id) -> prS/invS.
//  3. pack rank stream (0xFF = inactive) -> compact to zsB via prefix sums.
//  4. time-parallel Lindley scan: step f(a)=max(a+p,q); fill (p,q)=(x,-inf),
//     LRU (p,q)=(x-1,x); maps compose associatively -> segment (P,Q).
//     Pass1: 16 segments' (P,Q); combine -> entry a; window rewalk -> e.
//  5. qLast = emb[lastv] @ Wq + bq (register-pipelined GEMV).
//  6. scores -> count-weighted softmax regroup -> ctx -> logits; slow_mask.
// ---------------------------------------------------------------------------
__global__ __launch_bounds__(NT) void k_one(
    const int* __restrict__ seq, const float* __restrict__ emb,
    const float* __restrict__ Wg, const float* __restrict__ bg,
    const float* __restrict__ Wd, const float* __restrict__ bd,
    const float* __restrict__ Wq, const float* __restrict__ bq,
    const float* __restrict__ Wo, const float* __restrict__ bo,
    float* __restrict__ out) {
  const int b = blockIdx.x;
  const int tid = threadIdx.x;
  const int lane = tid & 63;
  const int wv = tid >> 6;

  __shared__ float embS[VOC * EPAD];                    // 65792 B
  __shared__ __align__(16) unsigned char zsB[2080];
  __shared__ float qLastS[HIDD], ctxS[HIDD];
  __shared__ float pp16[NW][64];                        // scores/logits partials
  __shared__ float gp16[NW][64], dp16[NW][64];
  __shared__ float qp4[4][HIDD];                        // qLast partials
  __shared__ float demS[64], wS[64];
  __shared__ int prS[64], invS[64], cntTok[64];
  __shared__ int CS[NW];
  __shared__ int PsS[NW][64], QsS[NW][64], eSS[NW][64];

  // ---- entry: seq into regs; stage emb (padded) ----
  const int2 sq = ((const int2*)(seq + b * TT))[tid];   // tokens 2t, 2t+1
  const int lastv = seq[b * TT + TT - 1];
  const float4* emb4 = (const float4*)emb;
  for (int i = tid; i < VOC * 64; i += NT) {
    float4 e = emb4[i];
    float* d = &embS[(i >> 6) * EPAD + ((i & 63) << 2)];
    d[0] = e.x; d[1] = e.y; d[2] = e.z; d[3] = e.w;
  }
  __syncthreads();

  // ---- gate/dem partial dots: thread = (v, kp in 0..15), 16 k each ----
  {
    const int v = tid & 63, kp = tid >> 6;
    const float* er = &embS[v * EPAD + kp * 16];
    const float* wg = &Wg[kp * 16];
    const float* wd = &Wd[kp * 16];
    float g = 0.f, d = 0.f;
#pragma unroll
    for (int k = 0; k < 16; ++k) { float e = er[k]; g += e * wg[k]; d += e * wd[k]; }
    gp16[kp][v] = g; dp16[kp][v] = d;
  }
  __syncthreads();
  // ---- act + rank merged (wave 0 only; wave-synchronous LDS, no barrier) ----
  if (tid < 64) {
    float g = bg[0], d = bd[0];
#pragma unroll
    for (int p = 0; p < NW; ++p) { g += gp16[p][tid]; d += dp16[p][tid]; }
    int act = (1.f / (1.f + expf(-g)) >= 0.4f) ? 1 : 0;
    demS[tid] = d;
    float dv = d;
    int r = 0;
    for (int u2 = 0; u2 < 64; ++u2) {
      float du = demS[u2];
      r += (du < dv || (du == dv && u2 < tid)) ? 1 : 0;
    }
    invS[r] = tid;
    prS[tid] = act ? r : 0xFF;
  }
  __syncthreads();

  // ---- pack 2 tokens -> rank bytes; per-wave prefix; scatter to zsB ----
  const int t0 = tid * 2;
  int by0, by1, c;
  {
    int r0 = prS[sq.x], r1 = prS[sq.y];
    by0 = (t0 < TLOOP) ? r0 : 0xFF;
    by1 = (t0 + 1 < TLOOP) ? r1 : 0xFF;
    c = ((by0 != 0xFF) ? 1 : 0) + ((by1 != 0xFF) ? 1 : 0);
  }
  int incl = c;
  for (int s = 1; s < 64; s <<= 1) {
    int t = __shfl_up(incl, s);
    if (lane >= s) incl += t;
  }
  if (lane == 63) CS[wv] = incl;
  __syncthreads();

  int Ow = 0, A = 0;
#pragma unroll
  for (int w2 = 0; w2 < NW; ++w2) {
    int cw = CS[w2];
    Ow += (w2 < wv) ? cw : 0;
    A += cw;
  }
  {
    int pos = Ow + incl - c;
    if (by0 != 0xFF) zsB[pos++] = (unsigned char)by0;
    if (by1 != 0xFF) zsB[pos++] = (unsigned char)by1;
  }
  __syncthreads();

  const int fsplit = A < 64 ? A : 64;
  const int nL = A - fsplit;
  const int win = nL < 256 ? nL : 256;
  const int wstart = A - win;
  const int L = (((A + NW - 1) / NW) + 15) & ~15;  // seg len, mult of 16
  const int baseW = wv * L;
  const int endW = min(baseW + L, A);

  // slow_mask store, overlapped with the scan (independent of it)
  if (tid < 256)
    out[BB * VOC + b * SLOWN + tid] = (tid < win) ? 1.0f : 0.0f;

  // T14: issue first half of Wq GEMV loads; land under pass 1
  const int jq = tid & 255, kq = tid >> 8, kb = kq * 64;
  float wqA[32];
#pragma unroll
  for (int k = 0; k < 32; ++k) wqA[k] = Wq[(kb + k) * HIDD + jq];

  // ---- pass 1: per-segment map (P,Q), lane = rank threshold ----
  int P = 0, Q = NEGBIG;
  for (int g = baseW; g < endW; g += 16) {
    uint4 t4 = *(const uint4*)(zsB + g);
    unsigned dsw[4] = {t4.x, t4.y, t4.z, t4.w};
    const int gHi = min(g + 16, endW);
    if (gHi == g + 16 && gHi <= fsplit) {            // FILL
#pragma unroll
      for (int d = 0; d < 4; ++d)
#pragma unroll
        for (int j = 0; j < 4; ++j) {
          int x = (BYTEAT(dsw[d], j) <= lane) ? 1 : 0;
          P += x; Q += x;
        }
    } else if (gHi == g + 16 && g >= fsplit) {       // LRU
#pragma unroll
      for (int d = 0; d < 4; ++d)
#pragma unroll
        for (int j = 0; j < 4; ++j) {
          int x = (BYTEAT(dsw[d], j) <= lane) ? 1 : 0;
          P += x - 1;
          Q = max(Q + x - 1, x);
        }
    } else {                                         // GATED
#pragma unroll
      for (int d = 0; d < 4; ++d)
#pragma unroll
        for (int j = 0; j < 4; ++j) {
          int i = g + d * 4 + j;
          int x = (BYTEAT(dsw[d], j) <= lane) ? 1 : 0;
          bool vld = i < endW;
          bool fil = i < fsplit;
          int p = fil ? x : x - 1;
          int q = fil ? NEGBIG : x;
          int Pn = P + p;
          int Qn = max(Q + p, q);
          P = vld ? Pn : P;
          Q = vld ? Qn : Q;
        }
    }
  }
  PsS[wv][lane] = P;
  QsS[wv][lane] = Q;
  __syncthreads();

  // consume Wq half 1; issue half 2 (lands under combine + window rewalk)
  float qacc = 0.f;
  {
    const float* eL = &embS[lastv * EPAD + kb];
#pragma unroll
    for (int k = 0; k < 32; ++k) qacc += eL[k] * wqA[k];
  }
  float wqB[32];
#pragma unroll
  for (int k = 0; k < 32; ++k) wqB[k] = Wq[(kb + 32 + k) * HIDD + jq];

  // ---- pass 2 (window waves only): combine -> entry a; rewalk for e ----
  int e = 0;
  const bool walkW = (endW > wstart);
  if (walkW) {
    int a = 0;
    for (int w2 = 0; w2 < wv; ++w2)
      a = max(a + PsS[w2][lane], QsS[w2][lane]);
    for (int g = baseW; g < endW; g += 16) {
      uint4 t4 = *(const uint4*)(zsB + g);
      unsigned dsw[4] = {t4.x, t4.y, t4.z, t4.w};
      const int gHi = min(g + 16, endW);
      const bool full = (gHi == g + 16);
      if (full && gHi <= fsplit) {                     // FILL
#pragma unroll
        for (int d = 0; d < 4; ++d)
#pragma unroll
          for (int j = 0; j < 4; ++j)
            a += (BYTEAT(dsw[d], j) <= lane) ? 1 : 0;
      } else if (full && g >= fsplit && gHi <= wstart) {  // MAIN
#pragma unroll
        for (int d = 0; d < 4; ++d)
#pragma unroll
          for (int j = 0; j < 4; ++j) {
            int xm1 = (BYTEAT(dsw[d], j) <= lane) ? 0 : -1;
            a = max(a, 1) + xm1;
          }
      } else if (full && g >= wstart) {                // WIN
#pragma unroll
        for (int d = 0; d < 4; ++d)
#pragma unroll
          for (int j = 0; j < 4; ++j) {
            int xm1 = (BYTEAT(dsw[d], j) <= lane) ? 0 : -1;
            e += (a > 0) ? 1 : 0;
            a = max(a, 1) + xm1;
          }
      } else {                                         // GATED
#pragma unroll
        for (int d = 0; d < 4; ++d)
#pragma unroll
          for (int j = 0; j < 4; ++j) {
            int i = g + d * 4 + j;
            int x = (BYTEAT(dsw[d], j) <= lane) ? 1 : 0;
            bool vld = i < endW;
            bool fil = i < fsplit;
            bool wg = vld && (i >= wstart);
            e += (wg && a > 0) ? 1 : 0;
            int af = a + x;
            int al = max(a, 1) + (x - 1);
            int an = fil ? af : al;
            a = vld ? an : a;
          }
      }
    }
  }
  eSS[wv][lane] = e;

  // consume Wq half 2
  {
    const float* eL = &embS[lastv * EPAD + kb + 32];
#pragma unroll
    for (int k = 0; k < 32; ++k) qacc += eL[k] * wqB[k];
  }
  qp4[kq][jq] = qacc;
  __syncthreads();

  // ---- finalize counts (wave 0): final a from combine of all 16 maps ----
  if (tid < 64) {
    int af = 0;
#pragma unroll
    for (int w2 = 0; w2 < NW; ++w2)
      af = max(af + PsS[w2][lane], QsS[w2][lane]);
    int et = 0;
#pragma unroll
    for (int w2 = 0; w2 < NW; ++w2) et += eSS[w2][lane];
    int ap = __shfl_up(af, 1); if (lane == 0) ap = 0;
    int ep = __shfl_up(et, 1); if (lane == 0) ep = 0;
    cntTok[invS[lane]] = (af - ap) + (et - ep);
  }
  // qLast reduce (wave0 also participates; same phase)
  if (tid < 256)
    qLastS[tid] = qp4[0][tid] + qp4[1][tid] + qp4[2][tid] + qp4[3][tid] + bq[tid];
  __syncthreads();

  // T14: prefetch Wo rows for the logits phase (lands under scores/softmax/ctx)
  const int o = tid & 63, part = tid >> 6;
  float wor[16];
#pragma unroll
  for (int k = 0; k < 16; ++k) wor[k] = Wo[((part << 4) + k) * VOC + o];

  // ---- scores sc[v] = emb[v].qLast ; softmax regroup over counts ----
  {
    const float* er = &embS[o * EPAD + part * 16];
    const float* qr = &qLastS[part * 16];
    float s = 0.f;
#pragma unroll
    for (int k = 0; k < 16; ++k) s += er[k] * qr[k];
    pp16[part][o] = s;
  }
  __syncthreads();
  if (tid < 64) {
    float sc = 0.f;
#pragma unroll
    for (int p = 0; p < NW; ++p) sc += pp16[p][tid];
    int cc = cntTok[tid];
    float m = (cc > 0) ? sc : NEGC;
    for (int off = 32; off; off >>= 1) m = fmaxf(m, __shfl_xor(m, off));
    float w = (cc > 0) ? (float)cc * expf(sc - m) : 0.f;
    float z = w;
    for (int off = 32; off; off >>= 1) z += __shfl_xor(z, off);
    z += (float)(FASTN + SLOWN - (fsplit + win)) * expf(NEGC - m);
    wS[tid] = w / z;
  }
  __syncthreads();

  // ---- ctx[h] = sum_u wS[u] * emb[u][h]  (256 threads, direct) ----
  if (tid < 256) {
    float cacc = 0.f;
#pragma unroll 16
    for (int u = 0; u < 64; ++u) cacc += wS[u] * embS[u * EPAD + tid];
    ctxS[tid] = cacc;
  }
  __syncthreads();

  // ---- logits = ctx @ Wo + bo  (Wo already in registers) ----
  {
    const float* cr = &ctxS[part * 16];
    float s = 0.f;
#pragma unroll
    for (int k = 0; k < 16; ++k) s += cr[k] * wor[k];
    pp16[part][o] = s;
  }
  __syncthreads();
  if (tid < 64) {
    float s = bo[tid];
#pragma unroll
    for (int p = 0; p < NW; ++p) s += pp16[p][tid];
    out[b * VOC + tid] = s;
  }
}

// ---------------------------------------------------------------------------
extern "C" void kernel_launch(void* const* d_in, const int* in_sizes, int n_in,
                              void* d_out, int out_size, void* d_ws, size_t ws_size,
                              hipStream_t stream) {
  const int*   seq = (const int*)d_in[0];
  const float* emb = (const float*)d_in[1];
  const float* Wg  = (const float*)d_in[2];
  const float* bg  = (const float*)d_in[3];
  const float* Wd  = (const float*)d_in[4];
  const float* bd  = (const float*)d_in[5];
  const float* Wq  = (const float*)d_in[6];
  const float* bq  = (const float*)d_in[7];
  const float* Wo  = (const float*)d_in[8];
  const float* bo  = (const float*)d_in[9];
  float* out = (float*)d_out;

  k_one<<<dim3(64), dim3(NT), 0, stream>>>(seq, emb, Wg, bg, Wd, bd,
                                           Wq, bq, Wo, bo, out);
}

// Round 3
// 85.463 us; speedup vs baseline: 1.1196x; 1.0363x over previous
//
#include <hip/hip_runtime.h>
#include <math.h>

#define BB 64
#define TT 2048
#define HIDD 256
#define FASTN 64
#define SLOWN 256
#define VOC 64
#define TLOOP (TT - 3)   // 2045 scan steps
#define NEGC -1000000000.0f
#define EPAD 257         // padded emb row stride (bank-conflict-free)
#define NEGBIG (-(1 << 20))
#define NW 16            // waves per block
#define NT (NW * 64)     // 1024 threads

// ---------------------------------------------------------------------------
// Single fused kernel (64 blocks x 1024 = 16 waves). vs previous version:
//  - pass 1 collapsed to SWAR popcounts: pure-LRU segment map composes to
//    (P,Q) = (cnt-len, x_last); FILL to (cnt,-inf). x computed 4 bytes/op via
//    ((lane|0x80)*0x01010101 - U) & 0x80808080 (valid: stream bytes <= 63).
//  - pass 2 closed form: a_j = max(a_in - z_j, x_{j-1}) monotone in zeros ->
//    e = n - max(0, Z' - a_in + 1), Z' = zeros among first n-1 window bytes.
//    No per-byte rewalk at all.
//  - Wq GEMV loads software-pipelined under the scan (T14 async split)
//  - Wo prefetched to registers before the scores phase
// Algorithm:
//  1. stage emb (padded) into LDS; seq into registers (int2/thread).
//  2. gate/dem dots -> act, dem; rank (ascending dem, tie by id) -> prS/invS.
//  3. pack rank stream (0xFF = inactive) -> compact to zsB via prefix sums;
//     zero 16 pad bytes at zsB[A..A+16) for safe SWAR tail reads.
//  4. time-parallel Lindley scan via composed maps (popcounts only).
//  5. qLast = emb[lastv] @ Wq + bq (register-pipelined GEMV).
//  6. scores -> count-weighted softmax regroup -> ctx -> logits; slow_mask.
// ---------------------------------------------------------------------------

// popcount of x = (byte <= lane) over byte range [lo, hi) of zs; LL8 =
// (lane*0x01010101)|0x80808080. Requires all readable bytes <= 127.
__device__ __forceinline__ int countx(const unsigned char* zs, int lo, int hi,
                                      unsigned LL8) {
  int cnt = 0;
  for (int d = lo & ~3; d < hi; d += 4) {
    unsigned U = *(const unsigned*)(zs + d);
    unsigned m = (LL8 - U) & 0x80808080u;
    if (d < lo) m &= 0x80808080u << ((lo - d) << 3);
    if (d + 4 > hi) m &= 0x80808080u >> ((d + 4 - hi) << 3);
    cnt += __popc(m);
  }
  return cnt;
}

__global__ __launch_bounds__(NT) void k_one(
    const int* __restrict__ seq, const float* __restrict__ emb,
    const float* __restrict__ Wg, const float* __restrict__ bg,
    const float* __restrict__ Wd, const float* __restrict__ bd,
    const float* __restrict__ Wq, const float* __restrict__ bq,
    const float* __restrict__ Wo, const float* __restrict__ bo,
    float* __restrict__ out) {
  const int b = blockIdx.x;
  const int tid = threadIdx.x;
  const int lane = tid & 63;
  const int wv = tid >> 6;

  __shared__ float embS[VOC * EPAD];                    // 65792 B
  __shared__ __align__(16) unsigned char zsB[2080];
  __shared__ float qLastS[HIDD], ctxS[HIDD];
  __shared__ float pp16[NW][64];                        // scores/logits partials
  __shared__ float gp16[NW][64], dp16[NW][64];
  __shared__ float qp4[4][HIDD];                        // qLast partials
  __shared__ float demS[64], wS[64];
  __shared__ int prS[64], invS[64], cntTok[64];
  __shared__ int CS[NW];
  __shared__ int PsS[NW][64], QsS[NW][64], eSS[NW][64];

  // ---- entry: seq into regs; stage emb (padded) ----
  const int2 sq = ((const int2*)(seq + b * TT))[tid];   // tokens 2t, 2t+1
  const int lastv = seq[b * TT + TT - 1];
  const float4* emb4 = (const float4*)emb;
  for (int i = tid; i < VOC * 64; i += NT) {
    float4 e = emb4[i];
    float* d = &embS[(i >> 6) * EPAD + ((i & 63) << 2)];
    d[0] = e.x; d[1] = e.y; d[2] = e.z; d[3] = e.w;
  }
  __syncthreads();

  // ---- gate/dem partial dots: thread = (v, kp in 0..15), 16 k each ----
  {
    const int v = tid & 63, kp = tid >> 6;
    const float* er = &embS[v * EPAD + kp * 16];
    const float* wg = &Wg[kp * 16];
    const float* wd = &Wd[kp * 16];
    float g = 0.f, d = 0.f;
#pragma unroll
    for (int k = 0; k < 16; ++k) { float e = er[k]; g += e * wg[k]; d += e * wd[k]; }
    gp16[kp][v] = g; dp16[kp][v] = d;
  }
  __syncthreads();
  // ---- act + rank merged (wave 0 only; wave-synchronous LDS, no barrier) ----
  if (tid < 64) {
    float g = bg[0], d = bd[0];
#pragma unroll
    for (int p = 0; p < NW; ++p) { g += gp16[p][tid]; d += dp16[p][tid]; }
    int act = (1.f / (1.f + expf(-g)) >= 0.4f) ? 1 : 0;
    demS[tid] = d;
    float dv = d;
    int r = 0;
    for (int u2 = 0; u2 < 64; ++u2) {
      float du = demS[u2];
      r += (du < dv || (du == dv && u2 < tid)) ? 1 : 0;
    }
    invS[r] = tid;
    prS[tid] = act ? r : 0xFF;
  }
  __syncthreads();

  // ---- pack 2 tokens -> rank bytes; per-wave prefix; scatter to zsB ----
  const int t0 = tid * 2;
  int by0, by1, c;
  {
    int r0 = prS[sq.x], r1 = prS[sq.y];
    by0 = (t0 < TLOOP) ? r0 : 0xFF;
    by1 = (t0 + 1 < TLOOP) ? r1 : 0xFF;
    c = ((by0 != 0xFF) ? 1 : 0) + ((by1 != 0xFF) ? 1 : 0);
  }
  int incl = c;
  for (int s = 1; s < 64; s <<= 1) {
    int t = __shfl_up(incl, s);
    if (lane >= s) incl += t;
  }
  if (lane == 63) CS[wv] = incl;
  __syncthreads();

  int Ow = 0, A = 0;
#pragma unroll
  for (int w2 = 0; w2 < NW; ++w2) {
    int cw = CS[w2];
    Ow += (w2 < wv) ? cw : 0;
    A += cw;
  }
  {
    int pos = Ow + incl - c;
    if (by0 != 0xFF) zsB[pos++] = (unsigned char)by0;
    if (by1 != 0xFF) zsB[pos++] = (unsigned char)by1;
  }
  if (tid < 16) zsB[A + tid] = 0;   // SWAR-safe tail pad (reads < A+16)
  __syncthreads();

  const int fsplit = A < 64 ? A : 64;
  const int nL = A - fsplit;
  const int win = nL < 256 ? nL : 256;
  const int wstart = A - win;
  const int L = (((A + NW - 1) / NW) + 15) & ~15;  // seg len, mult of 16
  const int baseW = wv * L;
  const int endW = min(baseW + L, A);

  // slow_mask store, overlapped with the scan (independent of it)
  if (tid < 256)
    out[BB * VOC + b * SLOWN + tid] = (tid < win) ? 1.0f : 0.0f;

  // T14: issue first half of Wq GEMV loads; land under pass 1
  const int jq = tid & 255, kq = tid >> 8, kb = kq * 64;
  float wqA[32];
#pragma unroll
  for (int k = 0; k < 32; ++k) wqA[k] = Wq[(kb + k) * HIDD + jq];

  // ---- pass 1: segment map (P,Q) via SWAR popcounts ----
  const unsigned LL8 = (unsigned)lane * 0x01010101u | 0x80808080u;
  const int fmin = min(endW, fsplit);          // end of FILL portion
  const int lf = max(baseW, fsplit);           // start of LRU portion
  const int wbl = max(lf, min(endW, wstart));  // start of window portion
  int cF = 0, cPre = 0, cWin = 0;
  if (fmin > baseW) cF = countx(zsB, baseW, fmin, LL8);
  if (wbl > lf) cPre = countx(zsB, lf, wbl, LL8);
  if (endW > wbl) cWin = countx(zsB, wbl, endW, LL8);
  const int lenL = endW - lf;
  {
    int P = cF + cPre + cWin - (lenL > 0 ? lenL : 0);
    int Q = (lenL > 0) ? ((zsB[endW - 1] <= lane) ? 1 : 0) : NEGBIG;
    PsS[wv][lane] = P;
    QsS[wv][lane] = Q;
  }
  __syncthreads();

  // consume Wq half 1; issue half 2 (lands under pass 2 + finalize)
  float qacc = 0.f;
  {
    const float* eL = &embS[lastv * EPAD + kb];
#pragma unroll
    for (int k = 0; k < 32; ++k) qacc += eL[k] * wqA[k];
  }
  float wqB[32];
#pragma unroll
  for (int k = 0; k < 32; ++k) wqB[k] = Wq[(kb + 32 + k) * HIDD + jq];

  // ---- pass 2 (window waves only): closed-form eviction count ----
  int e = 0;
  if (endW > wbl) {
    int a = 0;
    for (int w2 = 0; w2 < wv; ++w2)
      a = max(a + PsS[w2][lane], QsS[w2][lane]);
    a += cF;                                   // FILL portion: a -> a + cnt
    const int lenP = wbl - lf;                 // pre-window LRU portion
    if (lenP > 0) {
      int xl = (zsB[wbl - 1] <= lane) ? 1 : 0;
      a = max(a + cPre - lenP, xl);
    }
    const int n = endW - wbl;
    const int xw = (zsB[endW - 1] <= lane) ? 1 : 0;
    const int Zp = (n - cWin) - (1 - xw);      // zeros among first n-1 bytes
    const int F = max(0, Zp - a + 1);
    e = n - F;
  }
  eSS[wv][lane] = e;

  // consume Wq half 2
  {
    const float* eL = &embS[lastv * EPAD + kb + 32];
#pragma unroll
    for (int k = 0; k < 32; ++k) qacc += eL[k] * wqB[k];
  }
  qp4[kq][jq] = qacc;
  __syncthreads();

  // ---- finalize counts (wave 0): final a from combine of all 16 maps ----
  if (tid < 64) {
    int af = 0;
#pragma unroll
    for (int w2 = 0; w2 < NW; ++w2)
      af = max(af + PsS[w2][lane], QsS[w2][lane]);
    int et = 0;
#pragma unroll
    for (int w2 = 0; w2 < NW; ++w2) et += eSS[w2][lane];
    int ap = __shfl_up(af, 1); if (lane == 0) ap = 0;
    int ep = __shfl_up(et, 1); if (lane == 0) ep = 0;
    cntTok[invS[lane]] = (af - ap) + (et - ep);
  }
  // qLast reduce (same phase)
  if (tid < 256)
    qLastS[tid] = qp4[0][tid] + qp4[1][tid] + qp4[2][tid] + qp4[3][tid] + bq[tid];
  __syncthreads();

  // T14: prefetch Wo rows for the logits phase (lands under scores/softmax/ctx)
  const int o = tid & 63, part = tid >> 6;
  float wor[16];
#pragma unroll
  for (int k = 0; k < 16; ++k) wor[k] = Wo[((part << 4) + k) * VOC + o];

  // ---- scores sc[v] = emb[v].qLast ; softmax regroup over counts ----
  {
    const float* er = &embS[o * EPAD + part * 16];
    const float* qr = &qLastS[part * 16];
    float s = 0.f;
#pragma unroll
    for (int k = 0; k < 16; ++k) s += er[k] * qr[k];
    pp16[part][o] = s;
  }
  __syncthreads();
  if (tid < 64) {
    float sc = 0.f;
#pragma unroll
    for (int p = 0; p < NW; ++p) sc += pp16[p][tid];
    int cc = cntTok[tid];
    float m = (cc > 0) ? sc : NEGC;
    for (int off = 32; off; off >>= 1) m = fmaxf(m, __shfl_xor(m, off));
    float w = (cc > 0) ? (float)cc * expf(sc - m) : 0.f;
    float z = w;
    for (int off = 32; off; off >>= 1) z += __shfl_xor(z, off);
    z += (float)(FASTN + SLOWN - (fsplit + win)) * expf(NEGC - m);
    wS[tid] = w / z;
  }
  __syncthreads();

  // ---- ctx[h] = sum_u wS[u] * emb[u][h]  (256 threads, direct) ----
  if (tid < 256) {
    float cacc = 0.f;
#pragma unroll 16
    for (int u = 0; u < 64; ++u) cacc += wS[u] * embS[u * EPAD + tid];
    ctxS[tid] = cacc;
  }
  __syncthreads();

  // ---- logits = ctx @ Wo + bo  (Wo already in registers) ----
  {
    const float* cr = &ctxS[part * 16];
    float s = 0.f;
#pragma unroll
    for (int k = 0; k < 16; ++k) s += cr[k] * wor[k];
    pp16[part][o] = s;
  }
  __syncthreads();
  if (tid < 64) {
    float s = bo[tid];
#pragma unroll
    for (int p = 0; p < NW; ++p) s += pp16[p][tid];
    out[b * VOC + tid] = s;
  }
}

// ---------------------------------------------------------------------------
extern "C" void kernel_launch(void* const* d_in, const int* in_sizes, int n_in,
                              void* d_out, int out_size, void* d_ws, size_t ws_size,
                              hipStream_t stream) {
  const int*   seq = (const int*)d_in[0];
  const float* emb = (const float*)d_in[1];
  const float* Wg  = (const float*)d_in[2];
  const float* bg  = (const float*)d_in[3];
  const float* Wd  = (const float*)d_in[4];
  const float* bd  = (const float*)d_in[5];
  const float* Wq  = (const float*)d_in[6];
  const float* bq  = (const float*)d_in[7];
  const float* Wo  = (const float*)d_in[8];
  const float* bo  = (const float*)d_in[9];
  float* out = (float*)d_out;

  k_one<<<dim3(64), dim3(NT), 0, stream>>>(seq, emb, Wg, bg, Wd, bd,
                                           Wq, bq, Wo, bo, out);
}

// Round 4
// 84.826 us; speedup vs baseline: 1.1281x; 1.0075x over previous
//
#include <hip/hip_runtime.h>
#include <math.h>

#define BB 64
#define TT 2048
#define HIDD 256
#define FASTN 64
#define SLOWN 256
#define VOC 64
#define TLOOP (TT - 3)   // 2045 scan steps
#define NEGC -1000000000.0f
#define EPAD 257         // padded emb row stride (bank-conflict-free)
#define NEGBIG (-(1 << 20))
#define NW 16            // waves per block
#define NT (NW * 64)     // 1024 threads
#define ACTTH (-0.4054651081081644f)  // ln(2/3): sigmoid(x)>=0.4 <=> x>=ACTTH

// ---------------------------------------------------------------------------
// Single fused kernel (64 blocks x 1024 = 16 waves). vs previous version:
//  - gate/dem dots fused into emb staging (register data + 64-lane butterfly
//    all-reduce); gp16/dp16 phase and its barrier removed
//  - rank: each wave ranks its own 4 rows in parallel (1 LDS read + 4 cmp +
//    butterfly) instead of a 64-iter serial loop in wave 0
//  - act via logit threshold (no expf); bd dropped (rank is shift-invariant)
//  - wqA issued at kernel top; wqB issued before the pass-1 barrier
//  - finalize on wave 4, parallel with qLastS reduce (waves 0-3)
// Scan (unchanged from R3): SWAR popcount composed Lindley maps; pass 2 in
// closed form: e = n - max(0, Z' - a_in + 1).
// ---------------------------------------------------------------------------

// popcount of x = (byte <= lane) over byte range [lo, hi) of zs; LL8 =
// (lane*0x01010101)|0x80808080. Requires all readable bytes <= 127.
__device__ __forceinline__ int countx(const unsigned char* zs, int lo, int hi,
                                      unsigned LL8) {
  int cnt = 0;
  for (int d = lo & ~3; d < hi; d += 4) {
    unsigned U = *(const unsigned*)(zs + d);
    unsigned m = (LL8 - U) & 0x80808080u;
    if (d < lo) m &= 0x80808080u << ((lo - d) << 3);
    if (d + 4 > hi) m &= 0x80808080u >> ((d + 4 - hi) << 3);
    cnt += __popc(m);
  }
  return cnt;
}

__global__ __launch_bounds__(NT) void k_one(
    const int* __restrict__ seq, const float* __restrict__ emb,
    const float* __restrict__ Wg, const float* __restrict__ bg,
    const float* __restrict__ Wd, const float* __restrict__ bd,
    const float* __restrict__ Wq, const float* __restrict__ bq,
    const float* __restrict__ Wo, const float* __restrict__ bo,
    float* __restrict__ out) {
  const int b = blockIdx.x;
  const int tid = threadIdx.x;
  const int lane = tid & 63;
  const int wv = tid >> 6;

  __shared__ float embS[VOC * EPAD];                    // 65792 B
  __shared__ __align__(16) unsigned char zsB[2080];
  __shared__ float qLastS[HIDD], ctxS[HIDD];
  __shared__ float pp16[NW][64];                        // scores/logits partials
  __shared__ float qp4[4][HIDD];                        // qLast partials
  __shared__ float demS[64], wS[64];
  __shared__ int prS[64], invS[64], cntTok[64];
  __shared__ int CS[NW];
  __shared__ int PsS[NW][64], QsS[NW][64], eSS[NW][64];

  // ---- entry: seq into regs; issue Wq half 1 (lands under staging/rank) ----
  const int2 sq = ((const int2*)(seq + b * TT))[tid];   // tokens 2t, 2t+1
  const int lastv = seq[b * TT + TT - 1];
  const int jq = tid & 255, kq = tid >> 8, kb = kq * 64;
  float wqA[32];
#pragma unroll
  for (int k = 0; k < 32; ++k) wqA[k] = Wq[(kb + k) * HIDD + jq];

  const float4 Wg4 = ((const float4*)Wg)[lane];
  const float4 Wd4 = ((const float4*)Wd)[lane];
  const float bgv = bg[0];

  // ---- stage emb (padded) + fused gate/dem partial dots ----
  // thread covers rows wv+16c (c=0..3), cols 4*lane..4*lane+3
  float gc[4] = {0.f, 0.f, 0.f, 0.f}, dc[4] = {0.f, 0.f, 0.f, 0.f};
  const float4* emb4 = (const float4*)emb;
#pragma unroll
  for (int c2 = 0; c2 < 4; ++c2) {
    float4 e = emb4[c2 * 1024 + tid];
    float* dst = &embS[(wv + 16 * c2) * EPAD + (lane << 2)];
    dst[0] = e.x; dst[1] = e.y; dst[2] = e.z; dst[3] = e.w;
    gc[c2] += e.x * Wg4.x + e.y * Wg4.y + e.z * Wg4.z + e.w * Wg4.w;
    dc[c2] += e.x * Wd4.x + e.y * Wd4.y + e.z * Wd4.z + e.w * Wd4.w;
  }
  // butterfly all-reduce over 64 lanes (all lanes get identical sums)
#pragma unroll
  for (int off = 1; off < 64; off <<= 1) {
#pragma unroll
    for (int c2 = 0; c2 < 4; ++c2) {
      gc[c2] += __shfl_xor(gc[c2], off);
      dc[c2] += __shfl_xor(dc[c2], off);
    }
  }
  if (lane < 4) {
    float dv = lane == 0 ? dc[0] : lane == 1 ? dc[1] : lane == 2 ? dc[2] : dc[3];
    demS[wv + 16 * lane] = dv;
  }
  __syncthreads();

  // ---- rank: each wave ranks its own 4 rows (dem held in regs, all lanes) --
  {
    float du = demS[lane];
    int rc[4];
#pragma unroll
    for (int c2 = 0; c2 < 4; ++c2) {
      int v = wv + 16 * c2;
      rc[c2] = (du < dc[c2] || (du == dc[c2] && lane < v)) ? 1 : 0;
    }
#pragma unroll
    for (int off = 1; off < 64; off <<= 1) {
#pragma unroll
      for (int c2 = 0; c2 < 4; ++c2) rc[c2] += __shfl_xor(rc[c2], off);
    }
    if (lane < 4) {
      int rv = lane == 0 ? rc[0] : lane == 1 ? rc[1] : lane == 2 ? rc[2] : rc[3];
      float gv = lane == 0 ? gc[0] : lane == 1 ? gc[1] : lane == 2 ? gc[2] : gc[3];
      int v = wv + 16 * lane;
      int act = (gv + bgv >= ACTTH) ? 1 : 0;
      prS[v] = act ? rv : 0xFF;
      invS[rv] = v;
    }
  }
  __syncthreads();

  // ---- pack 2 tokens -> rank bytes; per-wave prefix; scatter to zsB ----
  const int t0 = tid * 2;
  int by0, by1, c;
  {
    int r0 = prS[sq.x], r1 = prS[sq.y];
    by0 = (t0 < TLOOP) ? r0 : 0xFF;
    by1 = (t0 + 1 < TLOOP) ? r1 : 0xFF;
    c = ((by0 != 0xFF) ? 1 : 0) + ((by1 != 0xFF) ? 1 : 0);
  }
  int incl = c;
  for (int s = 1; s < 64; s <<= 1) {
    int t = __shfl_up(incl, s);
    if (lane >= s) incl += t;
  }
  if (lane == 63) CS[wv] = incl;
  __syncthreads();

  int Ow = 0, A = 0;
#pragma unroll
  for (int w2 = 0; w2 < NW; ++w2) {
    int cw = CS[w2];
    Ow += (w2 < wv) ? cw : 0;
    A += cw;
  }
  {
    int pos = Ow + incl - c;
    if (by0 != 0xFF) zsB[pos++] = (unsigned char)by0;
    if (by1 != 0xFF) zsB[pos++] = (unsigned char)by1;
  }
  if (tid < 16) zsB[A + tid] = 0;   // SWAR-safe tail pad (reads < A+16)
  __syncthreads();

  const int fsplit = A < 64 ? A : 64;
  const int nL = A - fsplit;
  const int win = nL < 256 ? nL : 256;
  const int wstart = A - win;
  const int L = (((A + NW - 1) / NW) + 15) & ~15;  // seg len, mult of 16
  const int baseW = wv * L;
  const int endW = min(baseW + L, A);

  // slow_mask store, overlapped with the scan (independent of it)
  if (tid < 256)
    out[BB * VOC + b * SLOWN + tid] = (tid < win) ? 1.0f : 0.0f;

  // ---- pass 1: segment map (P,Q) via SWAR popcounts ----
  const unsigned LL8 = (unsigned)lane * 0x01010101u | 0x80808080u;
  const int fmin = min(endW, fsplit);          // end of FILL portion
  const int lf = max(baseW, fsplit);           // start of LRU portion
  const int wbl = max(lf, min(endW, wstart));  // start of window portion
  int cF = 0, cPre = 0, cWin = 0;
  if (fmin > baseW) cF = countx(zsB, baseW, fmin, LL8);
  if (wbl > lf) cPre = countx(zsB, lf, wbl, LL8);
  if (endW > wbl) cWin = countx(zsB, wbl, endW, LL8);
  const int lenL = endW - lf;
  {
    int P = cF + cPre + cWin - (lenL > 0 ? lenL : 0);
    int Q = (lenL > 0) ? ((zsB[endW - 1] <= lane) ? 1 : 0) : NEGBIG;
    PsS[wv][lane] = P;
    QsS[wv][lane] = Q;
  }
  // issue Wq half 2 now: lands under the barrier + wqA consume
  float wqB[32];
#pragma unroll
  for (int k = 0; k < 32; ++k) wqB[k] = Wq[(kb + 32 + k) * HIDD + jq];
  __syncthreads();

  // consume Wq half 1
  float qacc = 0.f;
  {
    const float* eL = &embS[lastv * EPAD + kb];
#pragma unroll
    for (int k = 0; k < 32; ++k) qacc += eL[k] * wqA[k];
  }

  // ---- pass 2 (window waves only): closed-form eviction count ----
  int e = 0;
  if (endW > wbl) {
    int a = 0;
    for (int w2 = 0; w2 < wv; ++w2)
      a = max(a + PsS[w2][lane], QsS[w2][lane]);
    a += cF;                                   // FILL portion: a -> a + cnt
    const int lenP = wbl - lf;                 // pre-window LRU portion
    if (lenP > 0) {
      int xl = (zsB[wbl - 1] <= lane) ? 1 : 0;
      a = max(a + cPre - lenP, xl);
    }
    const int n = endW - wbl;
    const int xw = (zsB[endW - 1] <= lane) ? 1 : 0;
    const int Zp = (n - cWin) - (1 - xw);      // zeros among first n-1 bytes
    const int F = max(0, Zp - a + 1);
    e = n - F;
  }
  eSS[wv][lane] = e;

  // consume Wq half 2
  {
    const float* eL = &embS[lastv * EPAD + kb + 32];
#pragma unroll
    for (int k = 0; k < 32; ++k) qacc += eL[k] * wqB[k];
  }
  qp4[kq][jq] = qacc;
  __syncthreads();

  // ---- finalize (wave 4) parallel with qLast reduce (waves 0-3) ----
  if (wv == 4) {
    int af = 0;
#pragma unroll
    for (int w2 = 0; w2 < NW; ++w2)
      af = max(af + PsS[w2][lane], QsS[w2][lane]);
    int et = 0;
#pragma unroll
    for (int w2 = 0; w2 < NW; ++w2) et += eSS[w2][lane];
    int ap = __shfl_up(af, 1); if (lane == 0) ap = 0;
    int ep = __shfl_up(et, 1); if (lane == 0) ep = 0;
    cntTok[invS[lane]] = (af - ap) + (et - ep);
  }
  if (tid < 256)
    qLastS[tid] = qp4[0][tid] + qp4[1][tid] + qp4[2][tid] + qp4[3][tid] + bq[tid];
  __syncthreads();

  // T14: prefetch Wo rows for the logits phase (lands under scores/softmax/ctx)
  const int o = tid & 63, part = tid >> 6;
  float wor[16];
#pragma unroll
  for (int k = 0; k < 16; ++k) wor[k] = Wo[((part << 4) + k) * VOC + o];

  // ---- scores sc[v] = emb[v].qLast ; softmax regroup over counts ----
  {
    const float* er = &embS[o * EPAD + part * 16];
    const float* qr = &qLastS[part * 16];
    float s = 0.f;
#pragma unroll
    for (int k = 0; k < 16; ++k) s += er[k] * qr[k];
    pp16[part][o] = s;
  }
  __syncthreads();
  if (tid < 64) {
    float sc = 0.f;
#pragma unroll
    for (int p = 0; p < NW; ++p) sc += pp16[p][tid];
    int cc = cntTok[tid];
    float m = (cc > 0) ? sc : NEGC;
    for (int off = 32; off; off >>= 1) m = fmaxf(m, __shfl_xor(m, off));
    float w = (cc > 0) ? (float)cc * expf(sc - m) : 0.f;
    float z = w;
    for (int off = 32; off; off >>= 1) z += __shfl_xor(z, off);
    z += (float)(FASTN + SLOWN - (fsplit + win)) * expf(NEGC - m);
    wS[tid] = w / z;
  }
  __syncthreads();

  // ---- ctx[h] = sum_u wS[u] * emb[u][h]  (256 threads, direct) ----
  if (tid < 256) {
    float cacc = 0.f;
#pragma unroll 16
    for (int u = 0; u < 64; ++u) cacc += wS[u] * embS[u * EPAD + tid];
    ctxS[tid] = cacc;
  }
  __syncthreads();

  // ---- logits = ctx @ Wo + bo  (Wo already in registers) ----
  {
    const float* cr = &ctxS[part * 16];
    float s = 0.f;
#pragma unroll
    for (int k = 0; k < 16; ++k) s += cr[k] * wor[k];
    pp16[part][o] = s;
  }
  __syncthreads();
  if (tid < 64) {
    float s = bo[tid];
#pragma unroll
    for (int p = 0; p < NW; ++p) s += pp16[p][tid];
    out[b * VOC + tid] = s;
  }
}

// ---------------------------------------------------------------------------
extern "C" void kernel_launch(void* const* d_in, const int* in_sizes, int n_in,
                              void* d_out, int out_size, void* d_ws, size_t ws_size,
                              hipStream_t stream) {
  const int*   seq = (const int*)d_in[0];
  const float* emb = (const float*)d_in[1];
  const float* Wg  = (const float*)d_in[2];
  const float* bg  = (const float*)d_in[3];
  const float* Wd  = (const float*)d_in[4];
  const float* bd  = (const float*)d_in[5];
  const float* Wq  = (const float*)d_in[6];
  const float* bq  = (const float*)d_in[7];
  const float* Wo  = (const float*)d_in[8];
  const float* bo  = (const float*)d_in[9];
  float* out = (float*)d_out;

  k_one<<<dim3(64), dim3(NT), 0, stream>>>(seq, emb, Wg, bg, Wd, bd,
                                           Wq, bq, Wo, bo, out);
}